// Round 3
// baseline (320.114 us; speedup 1.0000x reference)
//
#include <hip/hip_runtime.h>
#include <hip/hip_bf16.h>
#include <math.h>

// ---------------- constants ----------------
#define NP 512            // padded / grid size
#define NIMG 256
#define NDEL 32
#define NTH 240
#define NINT 250
#define SOS_ELEMS (512*512)

__device__ __forceinline__ int brev9(int i) { return (int)(__brev((unsigned)i) >> 23); }

// 512-point radix-2 DIT FFT over LDS, 256 threads, data pre-loaded bit-reversed.
// sign = -1 forward, +1 inverse (unscaled).
__device__ __forceinline__ void fft512(float2* s, int tid, float sign) {
  #pragma unroll
  for (int st = 0; st < 9; ++st) {
    int half = 1 << st;
    int j = tid & (half - 1);
    int i1 = ((tid >> st) << (st + 1)) + j;
    int i2 = i1 + half;
    float ang = sign * 3.14159265358979323846f * (float)j / (float)half;
    float sn, cs;
    __sincosf(ang, &sn, &cs);
    float2 a = s[i1], b = s[i2];
    float tr = b.x * cs - b.y * sn;
    float ti = b.x * sn + b.y * cs;
    s[i1] = make_float2(a.x + tr, a.y + ti);
    s[i2] = make_float2(a.x - tr, a.y - ti);
    __syncthreads();
  }
}

__device__ __forceinline__ float block_reduce256(float v) {
  #pragma unroll
  for (int o = 32; o > 0; o >>= 1) v += __shfl_down(v, o, 64);
  __shared__ float red[4];
  int lane = threadIdx.x & 63, wid = threadIdx.x >> 6;
  __syncthreads();
  if (lane == 0) red[wid] = v;
  __syncthreads();
  float r = 0.f;
  if (wid == 0 && lane == 0) r = red[0] + red[1] + red[2] + red[3];
  return r;
}

// ---------------- K0: init SoS + zero accumulators ----------------
__global__ __launch_bounds__(256) void k_init(float* sos, float* acc) {
  int t = blockIdx.x * 256 + threadIdx.x;
  sos[t] = 1499.363f;
  if (t < 4) acc[t] = 0.f;
}

// ---------------- K1: SIREN MLP + scatter (register-blocked fp32 GEMM) ----------------
// 64 points/block; 256 threads = 16 pg x 16 jg; thread tile = 4p x 8j.
// Single LDS h-buffer reused across layers (34 KB -> 4 blocks/CU).
#define MLP_P 64
__global__ __launch_bounds__(256, 4) void k_mlp(
    const float* __restrict__ W1, const float* __restrict__ b1,
    const float* __restrict__ W2, const float* __restrict__ b2,
    const float* __restrict__ W3, const float* __restrict__ b3,
    const float* __restrict__ W4v, const float* __restrict__ b4,
    const float* __restrict__ mgrid, const int* __restrict__ mask_idx,
    int M, float* __restrict__ sos) {
  __shared__ float hbuf[MLP_P][132];   // row pad 132 (16B-aligned rows, 2-way bank alias only)
  __shared__ float xy2[MLP_P][2];
  int tid = threadIdx.x;
  int base = blockIdx.x * MLP_P;
  if (tid < MLP_P * 2) {
    int p = tid >> 1, c = tid & 1;
    float v = 0.f;
    if (base + p < M) v = mgrid[(base + p) * 2 + c];
    xy2[p][c] = v;
  }
  __syncthreads();
  // layer 1: h = sin(30*(x@W1+b1)), 64x128 elems
  for (int e = tid; e < MLP_P * 128; e += 256) {
    int p = e >> 7, j = e & 127;
    hbuf[p][j] = sinf(30.f * (xy2[p][0] * W1[j] + xy2[p][1] * W1[128 + j] + b1[j]));
  }
  __syncthreads();

  int jg = tid & 15, pg = tid >> 4;
  int j0 = jg * 8, p0 = pg * 4;
  #pragma unroll
  for (int layer = 0; layer < 2; ++layer) {
    const float* W = layer ? W3 : W2;
    const float* bb = layer ? b3 : b2;
    const float4* Wv = (const float4*)W;
    float acc[4][8];
    #pragma unroll
    for (int i = 0; i < 4; ++i)
      #pragma unroll
      for (int j = 0; j < 8; ++j) acc[i][j] = 0.f;

    for (int k0 = 0; k0 < 128; k0 += 4) {
      float4 h4[4];
      #pragma unroll
      for (int i = 0; i < 4; ++i)
        h4[i] = *(const float4*)&hbuf[p0 + i][k0];
      #pragma unroll
      for (int kk = 0; kk < 4; ++kk) {
        int k = k0 + kk;
        float4 wa = Wv[k * 32 + (j0 >> 2)];
        float4 wb = Wv[k * 32 + (j0 >> 2) + 1];
        float wreg[8] = {wa.x, wa.y, wa.z, wa.w, wb.x, wb.y, wb.z, wb.w};
        #pragma unroll
        for (int i = 0; i < 4; ++i) {
          float hv = ((const float*)&h4[i])[kk];
          #pragma unroll
          for (int j = 0; j < 8; ++j) acc[i][j] += hv * wreg[j];
        }
      }
    }
    float breg[8];
    #pragma unroll
    for (int j = 0; j < 8; ++j) breg[j] = bb[j0 + j];
    __syncthreads();   // everyone done READING hbuf
    #pragma unroll
    for (int i = 0; i < 4; ++i) {
      float o[8];
      #pragma unroll
      for (int j = 0; j < 8; ++j) o[j] = sinf(30.f * (acc[i][j] + breg[j]));
      *(float4*)&hbuf[p0 + i][j0]     = make_float4(o[0], o[1], o[2], o[3]);
      *(float4*)&hbuf[p0 + i][j0 + 4] = make_float4(o[4], o[5], o[6], o[7]);
    }
    __syncthreads();
  }

  // layer 4 + scatter: 4 lanes per point
  {
    int p = tid >> 2, q = tid & 3;
    float s = 0.f;
    #pragma unroll
    for (int k = 0; k < 32; k += 4) {
      float4 h4 = *(const float4*)&hbuf[p][q * 32 + k];
      float4 w4 = *(const float4*)&W4v[q * 32 + k];
      s += h4.x * w4.x + h4.y * w4.y + h4.z * w4.z + h4.w * w4.w;
    }
    s += __shfl_down(s, 1, 64);
    s += __shfl_down(s, 2, 64);
    if (q == 0 && base + p < M)
      sos[mask_idx[base + p]] = (s + b4[0]) * 170.f + 1550.f;
  }
}

// ---------------- K2: wavefront ray integrals ----------------
// One block per theta, one thread per integration step. Trapezoid over
// uniform steps = (0.5 f0 + f1 + ... + 0.5 f_{N-1}) * (l/249).
__global__ __launch_bounds__(256) void k_wavefront(
    const float* __restrict__ sos, const float* __restrict__ xq_p,
    const float* __restrict__ yq_p, const float* __restrict__ x_vec,
    const float* __restrict__ y_vec, float* __restrict__ wfs) {
  int i = blockIdx.x;          // theta index
  int j = threadIdx.x;         // integration step
  float xq = xq_p[0], yq = yq_p[0];
  float r = sqrtf(xq * xq + yq * yq);
  float phi = atan2f(xq, yq);                 // note: atan2(x, y) per reference
  float th = (float)((double)i * (2.0 * M_PI / 239.0));
  float s = sinf(th - phi), cd = cosf(th - phi);
  const float R2 = 0.008f * 0.008f;
  float disc = fmaxf(R2 - (r * s) * (r * s), 0.f);
  float sq = sqrtf(disc);
  float l_in = sq + r * cd;
  float l_out = 2.f * sq * (cd >= 0.f ? 1.f : 0.f);
  float l = (r < 0.008f) ? l_in : l_out;
  float x0 = x_vec[0], dx = x_vec[1] - x_vec[0];
  float y0 = y_vec[0], dy = y_vec[1] - y_vec[0];
  float sinth = sinf(th), costh = cosf(th);
  float contrib = 0.f;
  if (j < NINT) {
    float sj = (float)j * (1.f / 249.f);
    int xi = (int)rintf((xq - l * sj * sinth - x0) / dx);
    int yi = (int)rintf((yq - l * sj * costh - y0) / dy);
    float sv = sos[(((-yi) & 511) << 9) + (xi & 511)];
    float f = 1.f - 1500.f / sv;
    float wgt = (j == 0 || j == NINT - 1) ? 0.5f : 1.f;
    contrib = wgt * f;
  }
  float tot = block_reduce256(contrib);
  if (threadIdx.x == 0) wfs[i] = tot * l * (1.f / 249.f);
}

// ---------------- K3: build windowed/shifted rows + forward row FFT ----------------
__global__ __launch_bounds__(256) void k_fwd_rows(const float* __restrict__ y_img,
                                                  float2* __restrict__ bufA) {
  __shared__ float2 s[512];
  int u = blockIdx.x, d = blockIdx.y;
  int tid = threadIdx.x;
  float2* out = bufA + ((size_t)d << 18) + ((size_t)u << 9);
  int a = (u + 256) & 511;
  if (a < 128 || a >= 384) {
    out[tid] = make_float2(0.f, 0.f);
    out[tid + 256] = make_float2(0.f, 0.f);
    return;
  }
  int r = a - 128;
  const float INV2S2 = (float)(0.6931471805599453 / 1406.25);  // 1/(2*sigma^2)
  float axr = (float)r - 127.5f;
  float gr = expf(-axr * axr * INV2S2);
  for (int vv = tid; vv < 512; vv += 256) {
    int b = (vv + 256) & 511;
    float val = 0.f;
    if (b >= 128 && b < 384) {
      int c = b - 128;
      float axc = (float)c - 127.5f;
      val = y_img[((size_t)d << 16) + (r << 8) + c] * gr * expf(-axc * axc * INV2S2);
    }
    s[brev9(vv)] = make_float2(val, 0.f);
  }
  __syncthreads();
  fft512(s, tid, -1.f);
  out[tid] = s[tid];
  out[tid + 256] = s[tid + 256];
}

// ---------------- K4: in-place paired-tile transpose (per channel) ----------------
__global__ __launch_bounds__(256) void k_transpose_ip(float2* __restrict__ buf) {
  int ti = blockIdx.x, tj = blockIdx.y, ch = blockIdx.z;
  if (ti > tj) return;
  float2* B = buf + ((size_t)ch << 18);
  __shared__ float2 At[32][33];
  __shared__ float2 Bt[32][33];
  int tid = threadIdx.x;
  for (int e = tid; e < 1024; e += 256) {
    int r = e >> 5, c = e & 31;
    At[r][c] = B[(size_t)(ti * 32 + r) * 512 + tj * 32 + c];
    if (ti != tj) Bt[r][c] = B[(size_t)(tj * 32 + r) * 512 + ti * 32 + c];
  }
  __syncthreads();
  for (int e = tid; e < 1024; e += 256) {
    int r = e >> 5, c = e & 31;
    B[(size_t)(tj * 32 + r) * 512 + ti * 32 + c] = At[c][r];
    if (ti != tj) B[(size_t)(ti * 32 + r) * 512 + tj * 32 + c] = Bt[c][r];
  }
}

// ---------------- K5: generic in-place row FFT ----------------
__global__ __launch_bounds__(256) void k_fft_rows(float2* __restrict__ buf, float sign, float scale) {
  __shared__ float2 s[512];
  int row = blockIdx.x, ch = blockIdx.y;
  float2* p = buf + ((size_t)ch << 18) + ((size_t)row << 9);
  int tid = threadIdx.x;
  s[brev9(tid)] = p[tid];
  s[brev9(tid + 256)] = p[tid + 256];
  __syncthreads();
  fft512(s, tid, sign);
  float2 r0 = s[tid], r1 = s[tid + 256];
  p[tid] = make_float2(r0.x * scale, r0.y * scale);
  p[tid + 256] = make_float2(r1.x * scale, r1.y * scale);
}

// ---------------- K6: deconvolution + data-loss ----------------
__device__ __forceinline__ float interp_wf(const float* wfs, float xn) {
  const float dxg = (float)(2.0 * M_PI / 239.0);
  float t = xn / dxg;
  int f = (int)floorf(t); f = min(max(f, 0), 239);
  int c = (int)ceilf(t);  c = min(max(c, 0), 239);
  float yf = wfs[f], yc = wfs[c];
  if (c == f) return yc;
  float xgf = (float)f * dxg;
  return yf + (yc - yf) * (xn - xgf) / ((float)(c - f) * dxg);
}

__global__ __launch_bounds__(256) void k_deconv(const float2* __restrict__ Yt,
                                                const float* __restrict__ delays,
                                                const float* __restrict__ wfs_g,
                                                float2* __restrict__ X,
                                                float* __restrict__ acc) {
  __shared__ float wfs[NTH];
  __shared__ float dly[NDEL];
  int tid = threadIdx.x;
  if (tid < NTH) wfs[tid] = wfs_g[tid];
  if (tid < NDEL) dly[tid] = delays[tid];
  __syncthreads();
  int u = blockIdx.x * 256 + tid;
  int v = blockIdx.y;
  const float inv_nd = 1.f / 0.02048f;   // 1/(n*d) for fftfreq, n*d = 2*L_IMG
  float fx = (float)(u < 256 ? u : u - 512) * inv_nd;
  float fy = (float)(v < 256 ? v : v - 512) * inv_nd;
  const float TWO_PI = 6.28318530717958647692f;
  float kk = TWO_PI * sqrtf(fx * fx + fy * fy);
  float th = atan2f(fy, fx);
  if (th < 0.f) th += TWO_PI;
  float w = interp_wf(wfs, th);
  float thpi = th + 3.14159265358979323846f;
  if (thpi >= TWO_PI) thpi -= TWO_PI;
  float wpi = interp_wf(wfs, thpi);

  float rhsr = 0.f, rhsi = 0.f, lhs = 0.f;
  float h2a[NDEL], aY[NDEL];
  #pragma unroll
  for (int dd = 0; dd < NDEL; ++dd) {
    float A = kk * (dly[dd] - w);    // H term0 = exp(-i*A)
    float B = kk * (dly[dd] - wpi);  // H term1 = exp(+i*B)
    float sa, ca, sb, cb;
    __sincosf(A, &sa, &ca);
    __sincosf(B, &sb, &cb);
    float Hr = 0.5f * (ca + cb);
    float Hi = 0.5f * (sb - sa);
    float2 Yv = Yt[((size_t)dd << 18) + ((size_t)v << 9) + u];
    rhsr += Yv.x * Hr + Yv.y * Hi;
    rhsi += Yv.y * Hr - Yv.x * Hi;
    float h2 = Hr * Hr + Hi * Hi;
    lhs += h2;
    h2a[dd] = h2;
    aY[dd] = sqrtf(Yv.x * Yv.x + Yv.y * Yv.y);
  }
  float Xr = rhsr / lhs, Xi = rhsi / lhs;
  X[((size_t)v << 9) + u] = make_float2(Xr, Xi);
  float aX = sqrtf(Xr * Xr + Xi * Xi);
  float lsum = 0.f;
  #pragma unroll
  for (int dd = 0; dd < NDEL; ++dd) {
    float diff = (aY[dd] - sqrtf(h2a[dd]) * aX) * kk;
    lsum += diff * diff;
  }
  float bs = block_reduce256(lsum);
  if (threadIdx.x == 0) atomicAdd(&acc[0], bs);
}

// ---------------- K9: final inverse row FFT + fftshift + real store ----------------
__global__ __launch_bounds__(256) void k_final_rows(const float2* __restrict__ buf,
                                                    float* __restrict__ xrec) {
  __shared__ float2 s[512];
  int arow = blockIdx.x;
  const float2* p = buf + ((size_t)arow << 9);
  int tid = threadIdx.x;
  s[brev9(tid)] = p[tid];
  s[brev9(tid + 256)] = p[tid + 256];
  __syncthreads();
  fft512(s, tid, +1.f);
  int orow = (arow + 256) & 511;
  const float sc = 1.f / 512.f;
  int b0 = tid, b1 = tid + 256;
  xrec[(orow << 9) + ((b0 + 256) & 511)] = s[b0].x * sc;
  xrec[(orow << 9) + ((b1 + 256) & 511)] = s[b1].x * sc;
}

// ---------------- K10: TV + L1 reductions ----------------
__global__ __launch_bounds__(256) void k_tvl1(const float* __restrict__ sos,
                                              const float* __restrict__ mask,
                                              float* __restrict__ acc) {
  int t = blockIdx.x * 256 + threadIdx.x;
  float s = sos[t];
  float m = mask[t];
  int i = t >> 9, j = t & 511;
  float tv = 0.f;
  if (i > 0) tv += fabsf((s - sos[t - 512]) * m);
  if (j > 0) tv += fabsf((s - sos[t - 1]) * m);
  float l1 = fabsf(s - 1550.f) * m;
  float tvb = block_reduce256(tv);
  float l1b = block_reduce256(l1);
  if (threadIdx.x == 0) {
    atomicAdd(&acc[1], tvb);
    atomicAdd(&acc[2], l1b);
  }
}

// ---------------- K11: finalize loss ----------------
__global__ void k_finalize(const float* __restrict__ acc, float* __restrict__ out) {
  out[0] = acc[0] * (1.f / 8388608.f) + 1e-3f * acc[1] + 1e-3f * (acc[2] * (1.f / 262144.f));
}

// ---------------- launch ----------------
extern "C" void kernel_launch(void* const* d_in, const int* in_sizes, int n_in,
                              void* d_out, int out_size, void* d_ws, size_t ws_size,
                              hipStream_t stream) {
  const float* W1 = (const float*)d_in[0];
  const float* b1 = (const float*)d_in[1];
  const float* W2 = (const float*)d_in[2];
  const float* b2 = (const float*)d_in[3];
  const float* W3 = (const float*)d_in[4];
  const float* b3 = (const float*)d_in[5];
  const float* W4 = (const float*)d_in[6];
  const float* b4 = (const float*)d_in[7];
  const float* y_img = (const float*)d_in[8];
  const float* delays = (const float*)d_in[9];
  const float* xq = (const float*)d_in[10];
  const float* yq = (const float*)d_in[11];
  const float* mgrid = (const float*)d_in[12];
  const float* mask = (const float*)d_in[13];
  const int* mask_idx = (const int*)d_in[14];
  const float* x_vec = (const float*)d_in[15];
  const float* y_vec = (const float*)d_in[16];
  const int M = in_sizes[14];

  float* out = (float*)d_out;
  float* xrec = out;                    // 262144
  float* sos = out + SOS_ELEMS;         // 262144
  float* loss = out + 2 * SOS_ELEMS;    // 1

  float* acc = (float*)d_ws;                                    // 4 floats
  float* wfs = (float*)((char*)d_ws + 1024);                    // 240 floats
  float2* bufA = (float2*)((char*)d_ws + 4096);                 // 32*512*512 c64 = 67.1 MB
  float2* bufX = (float2*)((char*)d_ws + 4096 + (size_t)NDEL * SOS_ELEMS * sizeof(float2)); // 2 MB

  k_init<<<1024, 256, 0, stream>>>(sos, acc);
  k_mlp<<<(M + MLP_P - 1) / MLP_P, 256, 0, stream>>>(W1, b1, W2, b2, W3, b3, W4, b4,
                                                     mgrid, mask_idx, M, sos);
  k_wavefront<<<NTH, 256, 0, stream>>>(sos, xq, yq, x_vec, y_vec, wfs);
  k_fwd_rows<<<dim3(512, NDEL), 256, 0, stream>>>(y_img, bufA);
  k_transpose_ip<<<dim3(16, 16, NDEL), 256, 0, stream>>>(bufA);
  k_fft_rows<<<dim3(512, NDEL), 256, 0, stream>>>(bufA, -1.f, 1.f);   // bufA is now Yt[d][v][u]
  k_deconv<<<dim3(2, 512), 256, 0, stream>>>(bufA, delays, wfs, bufX, acc);
  k_fft_rows<<<dim3(512, 1), 256, 0, stream>>>(bufX, +1.f, 1.f / 512.f); // ifft along u
  k_transpose_ip<<<dim3(16, 16, 1), 256, 0, stream>>>(bufX);
  k_final_rows<<<512, 256, 0, stream>>>(bufX, xrec);
  k_tvl1<<<1024, 256, 0, stream>>>(sos, mask, acc);
  k_finalize<<<1, 1, 0, stream>>>(acc, loss);
}

// Round 4
// 260.886 us; speedup vs baseline: 1.2270x; 1.2270x over previous
//
#include <hip/hip_runtime.h>
#include <hip/hip_bf16.h>
#include <math.h>

// ---------------- constants ----------------
#define NP 512            // padded / grid size
#define NIMG 256
#define NDEL 32
#define NTH 240
#define NINT 250
#define SOS_ELEMS (512*512)
#define RS 516            // LDS row stride (float2) for 8-row FFT tiles

__device__ __forceinline__ int brev9(int i) { return (int)(__brev((unsigned)i) >> 23); }

// 512-point radix-2 DIT FFT over LDS, 256 threads, data pre-loaded bit-reversed.
__device__ __forceinline__ void fft512(float2* s, int tid, float sign) {
  #pragma unroll
  for (int st = 0; st < 9; ++st) {
    int half = 1 << st;
    int j = tid & (half - 1);
    int i1 = ((tid >> st) << (st + 1)) + j;
    int i2 = i1 + half;
    float ang = sign * 3.14159265358979323846f * (float)j / (float)half;
    float sn, cs;
    __sincosf(ang, &sn, &cs);
    float2 a = s[i1], b = s[i2];
    float tr = b.x * cs - b.y * sn;
    float ti = b.x * sn + b.y * cs;
    s[i1] = make_float2(a.x + tr, a.y + ti);
    s[i2] = make_float2(a.x - tr, a.y - ti);
    __syncthreads();
  }
}

__device__ __forceinline__ float block_reduce256(float v) {
  #pragma unroll
  for (int o = 32; o > 0; o >>= 1) v += __shfl_down(v, o, 64);
  __shared__ float red[4];
  int lane = threadIdx.x & 63, wid = threadIdx.x >> 6;
  __syncthreads();
  if (lane == 0) red[wid] = v;
  __syncthreads();
  float r = 0.f;
  if (wid == 0 && lane == 0) r = red[0] + red[1] + red[2] + red[3];
  return r;
}

// ---------------- K0: init SoS + zero accumulators ----------------
__global__ __launch_bounds__(256) void k_init(float* sos, float* acc) {
  int t = blockIdx.x * 256 + threadIdx.x;
  sos[t] = 1499.363f;
  if (t < 4) acc[t] = 0.f;
}

// ---------------- K1: SIREN MLP + scatter ----------------
// 32 points/block (~1030 blocks, 4/CU); W tiles staged via LDS (coalesced);
// __sinf for activations. 256 thr = 16 pg(2 pts) x 16 jg(8 j).
#define MLP_P 32
__global__ __launch_bounds__(256) void k_mlp(
    const float* __restrict__ W1, const float* __restrict__ b1,
    const float* __restrict__ W2, const float* __restrict__ b2,
    const float* __restrict__ W3, const float* __restrict__ b3,
    const float* __restrict__ W4v, const float* __restrict__ b4,
    const float* __restrict__ mgrid, const int* __restrict__ mask_idx,
    int M, float* __restrict__ sos) {
  __shared__ float hbuf[MLP_P][132];
  __shared__ float wbuf[8][132];
  __shared__ float xy2[MLP_P][2];
  int tid = threadIdx.x;
  int base = blockIdx.x * MLP_P;
  if (tid < MLP_P * 2) {
    int p = tid >> 1, c = tid & 1;
    float v = 0.f;
    if (base + p < M) v = mgrid[(base + p) * 2 + c];
    xy2[p][c] = v;
  }
  __syncthreads();
  // layer 1: 32x128
  for (int e = tid; e < MLP_P * 128; e += 256) {
    int p = e >> 7, j = e & 127;
    hbuf[p][j] = __sinf(30.f * (xy2[p][0] * W1[j] + xy2[p][1] * W1[128 + j] + b1[j]));
  }
  __syncthreads();

  int jg = tid & 15, pg = tid >> 4;
  int j0 = jg * 8, p0 = pg * 2;
  int wr = tid >> 5, wc = (tid & 31) << 2;   // W-staging coords
  #pragma unroll
  for (int layer = 0; layer < 2; ++layer) {
    const float* W = layer ? W3 : W2;
    const float* bb = layer ? b3 : b2;
    float acc[2][8];
    #pragma unroll
    for (int i = 0; i < 2; ++i)
      #pragma unroll
      for (int j = 0; j < 8; ++j) acc[i][j] = 0.f;

    for (int k0 = 0; k0 < 128; k0 += 8) {
      // stage 8 k-rows of W into LDS (coalesced)
      *(float4*)&wbuf[wr][wc] = *(const float4*)&W[(k0 + wr) * 128 + wc];
      __syncthreads();
      #pragma unroll
      for (int kk = 0; kk < 8; ++kk) {
        float4 wa = *(const float4*)&wbuf[kk][j0];
        float4 wb = *(const float4*)&wbuf[kk][j0 + 4];
        float wreg[8] = {wa.x, wa.y, wa.z, wa.w, wb.x, wb.y, wb.z, wb.w};
        float h0v = hbuf[p0][k0 + kk];
        float h1v = hbuf[p0 + 1][k0 + kk];
        #pragma unroll
        for (int j = 0; j < 8; ++j) {
          acc[0][j] += h0v * wreg[j];
          acc[1][j] += h1v * wreg[j];
        }
      }
      __syncthreads();
    }
    float breg[8];
    #pragma unroll
    for (int j = 0; j < 8; ++j) breg[j] = bb[j0 + j];
    #pragma unroll
    for (int i = 0; i < 2; ++i) {
      float o[8];
      #pragma unroll
      for (int j = 0; j < 8; ++j) o[j] = __sinf(30.f * (acc[i][j] + breg[j]));
      *(float4*)&hbuf[p0 + i][j0]     = make_float4(o[0], o[1], o[2], o[3]);
      *(float4*)&hbuf[p0 + i][j0 + 4] = make_float4(o[4], o[5], o[6], o[7]);
    }
    __syncthreads();
  }

  // layer 4 + scatter: 8 lanes per point
  {
    int p = tid >> 3, q = tid & 7;
    float s = 0.f;
    #pragma unroll
    for (int k = 0; k < 16; k += 4) {
      float4 h4 = *(const float4*)&hbuf[p][q * 16 + k];
      float4 w4 = *(const float4*)&W4v[q * 16 + k];
      s += h4.x * w4.x + h4.y * w4.y + h4.z * w4.z + h4.w * w4.w;
    }
    s += __shfl_down(s, 1, 64);
    s += __shfl_down(s, 2, 64);
    s += __shfl_down(s, 4, 64);
    if (q == 0 && base + p < M)
      sos[mask_idx[base + p]] = (s + b4[0]) * 170.f + 1550.f;
  }
}

// ---------------- K2: wavefront ray integrals ----------------
__global__ __launch_bounds__(256) void k_wavefront(
    const float* __restrict__ sos, const float* __restrict__ xq_p,
    const float* __restrict__ yq_p, const float* __restrict__ x_vec,
    const float* __restrict__ y_vec, float* __restrict__ wfs) {
  int i = blockIdx.x;          // theta index
  int j = threadIdx.x;         // integration step
  float xq = xq_p[0], yq = yq_p[0];
  float r = sqrtf(xq * xq + yq * yq);
  float phi = atan2f(xq, yq);                 // note: atan2(x, y) per reference
  float th = (float)((double)i * (2.0 * M_PI / 239.0));
  float s = sinf(th - phi), cd = cosf(th - phi);
  const float R2 = 0.008f * 0.008f;
  float disc = fmaxf(R2 - (r * s) * (r * s), 0.f);
  float sq = sqrtf(disc);
  float l_in = sq + r * cd;
  float l_out = 2.f * sq * (cd >= 0.f ? 1.f : 0.f);
  float l = (r < 0.008f) ? l_in : l_out;
  float x0 = x_vec[0], dx = x_vec[1] - x_vec[0];
  float y0 = y_vec[0], dy = y_vec[1] - y_vec[0];
  float sinth = sinf(th), costh = cosf(th);
  float contrib = 0.f;
  if (j < NINT) {
    float sj = (float)j * (1.f / 249.f);
    int xi = (int)rintf((xq - l * sj * sinth - x0) / dx);
    int yi = (int)rintf((yq - l * sj * costh - y0) / dy);
    float sv = sos[(((-yi) & 511) << 9) + (xi & 511)];
    float f = 1.f - 1500.f / sv;
    float wgt = (j == 0 || j == NINT - 1) ? 0.5f : 1.f;
    contrib = wgt * f;
  }
  float tot = block_reduce256(contrib);
  if (threadIdx.x == 0) wfs[i] = tot * l * (1.f / 249.f);
}

// ---------------- K3: windowed row-FFT (v axis), compact TRANSPOSED store ----
// Block = (8 image rows, channel). Output bufA[d][v][r], r in [0,256).
// Compact index r == image row (zero padded-u rows never stored).
__global__ __launch_bounds__(256) void k_fwdT(const float* __restrict__ y_img,
                                              float2* __restrict__ bufA) {
  __shared__ float2 s[8][RS];
  int rt = blockIdx.x;   // row tile [0,32)
  int d = blockIdx.y;
  int tid = threadIdx.x;
  const float INV2S2 = (float)(0.6931471805599453 / 1406.25);  // 1/(2*sigma^2)
  // zero
  for (int e = tid; e < 8 * 512; e += 256) s[e >> 9][e & 511] = make_float2(0.f, 0.f);
  __syncthreads();
  // load + window + bit-reversed placement (ifftshift along v: vv=(c+384)&511)
  for (int e = tid; e < 2048; e += 256) {
    int i = e >> 8, c = e & 255;
    int r = rt * 8 + i;
    float axr = (float)r - 127.5f;
    float axc = (float)c - 127.5f;
    float g = __expf(-(axr * axr + axc * axc) * INV2S2);
    float val = y_img[((size_t)d << 16) + (r << 8) + c] * g;
    s[i][brev9((c + 384) & 511)] = make_float2(val, 0.f);
  }
  __syncthreads();
  // 8 interleaved forward FFTs
  #pragma unroll
  for (int st = 0; st < 9; ++st) {
    int half = 1 << st;
    int j = tid & (half - 1);
    int i1 = ((tid >> st) << (st + 1)) + j;
    int i2 = i1 + half;
    float ang = -3.14159265358979323846f * (float)j / (float)half;
    float sn, cs;
    __sincosf(ang, &sn, &cs);
    #pragma unroll
    for (int i = 0; i < 8; ++i) {
      float2 a = s[i][i1], b = s[i][i2];
      float tr = b.x * cs - b.y * sn;
      float ti = b.x * sn + b.y * cs;
      s[i][i1] = make_float2(a.x + tr, a.y + ti);
      s[i][i2] = make_float2(a.x - tr, a.y - ti);
    }
    __syncthreads();
  }
  // transposed store: bufA[d][v][rt*8+i], 64B segments
  float2* out = bufA + ((size_t)d << 17) + rt * 8;
  for (int e = tid; e < 4096; e += 256) {
    int i = e & 7, v = e >> 3;
    out[(size_t)v * 256 + i] = s[i][v];
  }
}

// ---------------- K4: fused column-FFT (u axis) + deconv + data loss ----------
// Block = one v column. Loops 4 chunks x 8 channels through LDS.
__device__ __forceinline__ float interp_wf(const float* wfs, float xn) {
  const float dxg = (float)(2.0 * M_PI / 239.0);
  float t = xn / dxg;
  int f = (int)floorf(t); f = min(max(f, 0), 239);
  int c = (int)ceilf(t);  c = min(max(c, 0), 239);
  float yf = wfs[f], yc = wfs[c];
  if (c == f) return yc;
  float xgf = (float)f * dxg;
  return yf + (yc - yf) * (xn - xgf) / ((float)(c - f) * dxg);
}

__global__ __launch_bounds__(256) void k_colfft_deconv(
    const float2* __restrict__ bufA, const float* __restrict__ delays,
    const float* __restrict__ wfs_g, float2* __restrict__ X,
    float* __restrict__ acc) {
  __shared__ float2 s[8][RS];
  __shared__ float wfs[NTH];
  __shared__ float dly[NDEL];
  int v = blockIdx.x;
  int tid = threadIdx.x;
  if (tid < NTH) wfs[tid] = wfs_g[tid];
  if (tid < NDEL) dly[tid] = delays[tid];
  __syncthreads();

  // per-u precompute (u = tid, tid+256)
  const float inv_nd = 1.f / 0.02048f;
  const float TWO_PI = 6.28318530717958647692f;
  float fy = (float)(v < 256 ? v : v - 512) * inv_nd;
  float kkA[2], wA[2], wpiA[2];
  #pragma unroll
  for (int uu = 0; uu < 2; ++uu) {
    int u = tid + 256 * uu;
    float fx = (float)(u < 256 ? u : u - 512) * inv_nd;
    kkA[uu] = TWO_PI * sqrtf(fx * fx + fy * fy);
    float th = atan2f(fy, fx);
    if (th < 0.f) th += TWO_PI;
    wA[uu] = interp_wf(wfs, th);
    float thpi = th + 3.14159265358979323846f;
    if (thpi >= TWO_PI) thpi -= TWO_PI;
    wpiA[uu] = interp_wf(wfs, thpi);
  }

  float rhsr[2] = {0.f, 0.f}, rhsi[2] = {0.f, 0.f}, lhs[2] = {0.f, 0.f};
  float sY2[2] = {0.f, 0.f}, sYH[2] = {0.f, 0.f};

  for (int c4 = 0; c4 < 4; ++c4) {
    __syncthreads();   // previous chunk's reads done
    for (int e = tid; e < 8 * 512; e += 256) s[e >> 9][e & 511] = make_float2(0.f, 0.f);
    __syncthreads();
    // load 8 compact channel rows; place at padded u=(c+384)&511, bit-reversed
    for (int e = tid; e < 2048; e += 256) {
      int ch = e >> 8, c = e & 255;
      float2 val = bufA[((size_t)(c4 * 8 + ch) << 17) + (size_t)v * 256 + c];
      s[ch][brev9((c + 384) & 511)] = val;
    }
    __syncthreads();
    // 8 interleaved forward FFTs along u
    #pragma unroll
    for (int st = 0; st < 9; ++st) {
      int half = 1 << st;
      int j = tid & (half - 1);
      int i1 = ((tid >> st) << (st + 1)) + j;
      int i2 = i1 + half;
      float ang = -3.14159265358979323846f * (float)j / (float)half;
      float sn, cs;
      __sincosf(ang, &sn, &cs);
      #pragma unroll
      for (int i = 0; i < 8; ++i) {
        float2 a = s[i][i1], b = s[i][i2];
        float tr = b.x * cs - b.y * sn;
        float ti = b.x * sn + b.y * cs;
        s[i][i1] = make_float2(a.x + tr, a.y + ti);
        s[i][i2] = make_float2(a.x - tr, a.y - ti);
      }
      __syncthreads();
    }
    // accumulate deconv + loss moments
    #pragma unroll
    for (int uu = 0; uu < 2; ++uu) {
      int u = tid + 256 * uu;
      float kk = kkA[uu], w = wA[uu], wpi = wpiA[uu];
      #pragma unroll
      for (int ch = 0; ch < 8; ++ch) {
        float dl = dly[c4 * 8 + ch];
        float A = kk * (dl - w);
        float B = kk * (dl - wpi);
        float sa, ca, sb, cb;
        __sincosf(A, &sa, &ca);
        __sincosf(B, &sb, &cb);
        float Hr = 0.5f * (ca + cb);
        float Hi = 0.5f * (sb - sa);
        float2 Yv = s[ch][u];
        rhsr[uu] += Yv.x * Hr + Yv.y * Hi;
        rhsi[uu] += Yv.y * Hr - Yv.x * Hi;
        float h2 = Hr * Hr + Hi * Hi;
        float y2 = Yv.x * Yv.x + Yv.y * Yv.y;
        lhs[uu] += h2;
        sY2[uu] += y2;
        sYH[uu] += sqrtf(y2 * h2);
      }
    }
  }
  // finalize X + loss
  float lsum = 0.f;
  #pragma unroll
  for (int uu = 0; uu < 2; ++uu) {
    int u = tid + 256 * uu;
    float Xr = rhsr[uu] / lhs[uu], Xi = rhsi[uu] / lhs[uu];
    X[((size_t)v << 9) + u] = make_float2(Xr, Xi);
    float aX = sqrtf(Xr * Xr + Xi * Xi);
    float kk2 = kkA[uu] * kkA[uu];
    lsum += kk2 * (sY2[uu] - 2.f * aX * sYH[uu] + aX * aX * lhs[uu]);
  }
  float bs = block_reduce256(lsum);
  if (threadIdx.x == 0) atomicAdd(&acc[0], bs);
}

// ---------------- K5: generic in-place row FFT ----------------
__global__ __launch_bounds__(256) void k_fft_rows(float2* __restrict__ buf, float sign, float scale) {
  __shared__ float2 s[512];
  int row = blockIdx.x, ch = blockIdx.y;
  float2* p = buf + ((size_t)ch << 18) + ((size_t)row << 9);
  int tid = threadIdx.x;
  s[brev9(tid)] = p[tid];
  s[brev9(tid + 256)] = p[tid + 256];
  __syncthreads();
  fft512(s, tid, sign);
  float2 r0 = s[tid], r1 = s[tid + 256];
  p[tid] = make_float2(r0.x * scale, r0.y * scale);
  p[tid + 256] = make_float2(r1.x * scale, r1.y * scale);
}

// ---------------- K6: in-place paired-tile transpose (per channel) ----------------
__global__ __launch_bounds__(256) void k_transpose_ip(float2* __restrict__ buf) {
  int ti = blockIdx.x, tj = blockIdx.y, ch = blockIdx.z;
  if (ti > tj) return;
  float2* B = buf + ((size_t)ch << 18);
  __shared__ float2 At[32][33];
  __shared__ float2 Bt[32][33];
  int tid = threadIdx.x;
  for (int e = tid; e < 1024; e += 256) {
    int r = e >> 5, c = e & 31;
    At[r][c] = B[(size_t)(ti * 32 + r) * 512 + tj * 32 + c];
    if (ti != tj) Bt[r][c] = B[(size_t)(tj * 32 + r) * 512 + ti * 32 + c];
  }
  __syncthreads();
  for (int e = tid; e < 1024; e += 256) {
    int r = e >> 5, c = e & 31;
    B[(size_t)(tj * 32 + r) * 512 + ti * 32 + c] = At[c][r];
    if (ti != tj) B[(size_t)(ti * 32 + r) * 512 + tj * 32 + c] = Bt[c][r];
  }
}

// ---------------- K9: final inverse row FFT + fftshift + real store ----------------
__global__ __launch_bounds__(256) void k_final_rows(const float2* __restrict__ buf,
                                                    float* __restrict__ xrec) {
  __shared__ float2 s[512];
  int arow = blockIdx.x;
  const float2* p = buf + ((size_t)arow << 9);
  int tid = threadIdx.x;
  s[brev9(tid)] = p[tid];
  s[brev9(tid + 256)] = p[tid + 256];
  __syncthreads();
  fft512(s, tid, +1.f);
  int orow = (arow + 256) & 511;
  const float sc = 1.f / 512.f;
  int b0 = tid, b1 = tid + 256;
  xrec[(orow << 9) + ((b0 + 256) & 511)] = s[b0].x * sc;
  xrec[(orow << 9) + ((b1 + 256) & 511)] = s[b1].x * sc;
}

// ---------------- K10: TV + L1 reductions ----------------
__global__ __launch_bounds__(256) void k_tvl1(const float* __restrict__ sos,
                                              const float* __restrict__ mask,
                                              float* __restrict__ acc) {
  int t = blockIdx.x * 256 + threadIdx.x;
  float s = sos[t];
  float m = mask[t];
  int i = t >> 9, j = t & 511;
  float tv = 0.f;
  if (i > 0) tv += fabsf((s - sos[t - 512]) * m);
  if (j > 0) tv += fabsf((s - sos[t - 1]) * m);
  float l1 = fabsf(s - 1550.f) * m;
  float tvb = block_reduce256(tv);
  float l1b = block_reduce256(l1);
  if (threadIdx.x == 0) {
    atomicAdd(&acc[1], tvb);
    atomicAdd(&acc[2], l1b);
  }
}

// ---------------- K11: finalize loss ----------------
__global__ void k_finalize(const float* __restrict__ acc, float* __restrict__ out) {
  out[0] = acc[0] * (1.f / 8388608.f) + 1e-3f * acc[1] + 1e-3f * (acc[2] * (1.f / 262144.f));
}

// ---------------- launch ----------------
extern "C" void kernel_launch(void* const* d_in, const int* in_sizes, int n_in,
                              void* d_out, int out_size, void* d_ws, size_t ws_size,
                              hipStream_t stream) {
  const float* W1 = (const float*)d_in[0];
  const float* b1 = (const float*)d_in[1];
  const float* W2 = (const float*)d_in[2];
  const float* b2 = (const float*)d_in[3];
  const float* W3 = (const float*)d_in[4];
  const float* b3 = (const float*)d_in[5];
  const float* W4 = (const float*)d_in[6];
  const float* b4 = (const float*)d_in[7];
  const float* y_img = (const float*)d_in[8];
  const float* delays = (const float*)d_in[9];
  const float* xq = (const float*)d_in[10];
  const float* yq = (const float*)d_in[11];
  const float* mgrid = (const float*)d_in[12];
  const float* mask = (const float*)d_in[13];
  const int* mask_idx = (const int*)d_in[14];
  const float* x_vec = (const float*)d_in[15];
  const float* y_vec = (const float*)d_in[16];
  const int M = in_sizes[14];

  float* out = (float*)d_out;
  float* xrec = out;                    // 262144
  float* sos = out + SOS_ELEMS;         // 262144
  float* loss = out + 2 * SOS_ELEMS;    // 1

  float* acc = (float*)d_ws;                                    // 4 floats
  float* wfs = (float*)((char*)d_ws + 1024);                    // 240 floats
  float2* bufA = (float2*)((char*)d_ws + 4096);                 // 32*512*256 c64 = 33.6 MB
  float2* bufX = (float2*)((char*)d_ws + 4096 + (size_t)NDEL * 512 * 256 * sizeof(float2)); // 2 MB

  k_init<<<1024, 256, 0, stream>>>(sos, acc);
  k_mlp<<<(M + MLP_P - 1) / MLP_P, 256, 0, stream>>>(W1, b1, W2, b2, W3, b3, W4, b4,
                                                     mgrid, mask_idx, M, sos);
  k_wavefront<<<NTH, 256, 0, stream>>>(sos, xq, yq, x_vec, y_vec, wfs);
  k_fwdT<<<dim3(32, NDEL), 256, 0, stream>>>(y_img, bufA);
  k_colfft_deconv<<<512, 256, 0, stream>>>(bufA, delays, wfs, bufX, acc);
  k_fft_rows<<<dim3(512, 1), 256, 0, stream>>>(bufX, +1.f, 1.f / 512.f); // ifft along u
  k_transpose_ip<<<dim3(16, 16, 1), 256, 0, stream>>>(bufX);
  k_final_rows<<<512, 256, 0, stream>>>(bufX, xrec);
  k_tvl1<<<1024, 256, 0, stream>>>(sos, mask, acc);
  k_finalize<<<1, 1, 0, stream>>>(acc, loss);
}